// Round 10
// baseline (1269.405 us; speedup 1.0000x reference)
//
#include <hip/hip_runtime.h>
#include <math.h>

// Problem constants (match reference)
#define B_ 2
#define T_ 2048
#define M_ 768
#define R_ 64
#define S_ 16
#define MS_ (M_ * S_)
#define NC 128
#define CL 16              // T_ / NC
#define NMT 12             // m-tiles of 64
#define LOG2E 1.4426950408889634f
#define LOG2_EPS (-33.219280948873623f)   // log2(1e-10)

// --------------------------------------------------------------------------
// Kernel 1 (round-5 proven): dt = clip(softplus(delta . dt_w^T + b)).
// Tiled 64x64, K=64, LDS transpose staging, coalesced everywhere.
// --------------------------------------------------------------------------
__global__ __launch_bounds__(256) void dt_kernel(
    const float* __restrict__ delta,   // [B*T][R]
    const float* __restrict__ dt_w,    // [M][R]
    const float* __restrict__ dt_b,    // [M]
    float* __restrict__ dt_out)        // [B*T][M]
{
  __shared__ float ds_d[R_][68];
  __shared__ float ds_w[R_][68];
  const int tid = threadIdx.x;
  const int m0  = blockIdx.x * 64;
  const int bt0 = blockIdx.y * 64;

  #pragma unroll
  for (int k = 0; k < 4; ++k) {
    int idx = tid + k * 256;
    int rq = idx & 15;
    int x  = idx >> 4;
    float4 dv = *reinterpret_cast<const float4*>(&delta[(size_t)(bt0 + x) * R_ + rq * 4]);
    ds_d[rq * 4 + 0][x] = dv.x; ds_d[rq * 4 + 1][x] = dv.y;
    ds_d[rq * 4 + 2][x] = dv.z; ds_d[rq * 4 + 3][x] = dv.w;
    float4 wv = *reinterpret_cast<const float4*>(&dt_w[(size_t)(m0 + x) * R_ + rq * 4]);
    ds_w[rq * 4 + 0][x] = wv.x; ds_w[rq * 4 + 1][x] = wv.y;
    ds_w[rq * 4 + 2][x] = wv.z; ds_w[rq * 4 + 3][x] = wv.w;
  }
  __syncthreads();

  const int mq = tid & 15, tq = tid >> 4;
  const int ml = mq * 4, tl = tq * 4;
  float acc[4][4] = {};
  #pragma unroll 4
  for (int r = 0; r < R_; ++r) {
    float4 dv = *reinterpret_cast<const float4*>(&ds_d[r][tl]);
    float4 wv = *reinterpret_cast<const float4*>(&ds_w[r][ml]);
    float d[4] = {dv.x, dv.y, dv.z, dv.w};
    float w[4] = {wv.x, wv.y, wv.z, wv.w};
    #pragma unroll
    for (int i = 0; i < 4; ++i)
      #pragma unroll
      for (int j = 0; j < 4; ++j)
        acc[i][j] = fmaf(d[i], w[j], acc[i][j]);
  }

  float4 bb = *reinterpret_cast<const float4*>(&dt_b[m0 + ml]);
  float bv[4] = {bb.x, bb.y, bb.z, bb.w};
  #pragma unroll
  for (int i = 0; i < 4; ++i) {
    float4 o;
    float* op = &o.x;
    #pragma unroll
    for (int j = 0; j < 4; ++j) {
      float x = acc[i][j] + bv[j];
      float sp = (x > 20.f) ? x : __logf(1.f + __expf(x));
      op[j] = fminf(fmaxf(sp, 1e-6f), 10.f);
    }
    *reinterpret_cast<float4*>(&dt_out[(size_t)(bt0 + tl + i) * M_ + m0 + ml]) = o;
  }
}

// --------------------------------------------------------------------------
// Kernel 2 (bc v6, proven): register-cached W slices, fold+pack butterfly.
// --------------------------------------------------------------------------
__global__ __launch_bounds__(512, 4) void bc_kernel(
    const float* __restrict__ u,     // [B*T][M]
    const float* __restrict__ B_w,   // [S][M]
    const float* __restrict__ C_w,   // [S][M]
    float* __restrict__ Bm,          // [B*T][S]
    float* __restrict__ Cm)          // [B*T][S]
{
  const int wave = threadIdx.x >> 6, lane = threadIdx.x & 63;
  const int bt0 = blockIdx.x * 8;

  float4 w[4][3];
  #pragma unroll
  for (int s = 0; s < 4; ++s) {
    const int s_g = wave * 4 + s;
    const float* wr = (s_g < 16) ? &B_w[(size_t)s_g * M_] : &C_w[(size_t)(s_g - 16) * M_];
    const float4* w4 = reinterpret_cast<const float4*>(wr);
    w[s][0] = w4[lane]; w[s][1] = w4[64 + lane]; w[s][2] = w4[128 + lane];
  }

  float acc[32];
  #pragma unroll
  for (int r = 0; r < 8; ++r) {
    const float4* ur = reinterpret_cast<const float4*>(&u[(size_t)(bt0 + r) * M_]);
    const float4 a0 = ur[lane], a1 = ur[64 + lane], a2 = ur[128 + lane];
    #pragma unroll
    for (int s = 0; s < 4; ++s) {
      float t = 0.f;
      t = fmaf(a0.x, w[s][0].x, t); t = fmaf(a0.y, w[s][0].y, t);
      t = fmaf(a0.z, w[s][0].z, t); t = fmaf(a0.w, w[s][0].w, t);
      t = fmaf(a1.x, w[s][1].x, t); t = fmaf(a1.y, w[s][1].y, t);
      t = fmaf(a1.z, w[s][1].z, t); t = fmaf(a1.w, w[s][1].w, t);
      t = fmaf(a2.x, w[s][2].x, t); t = fmaf(a2.y, w[s][2].y, t);
      t = fmaf(a2.z, w[s][2].z, t); t = fmaf(a2.w, w[s][2].w, t);
      acc[r * 4 + s] = t;
    }
  }

  #pragma unroll
  for (int j = 0; j < 32; ++j) acc[j] += __shfl_xor(acc[j], 32);
  int cnt = 32;
  #pragma unroll
  for (int mask = 16; mask >= 1; mask >>= 1) {
    cnt >>= 1;
    const bool up = (lane & mask) != 0;
    #pragma unroll
    for (int j = 0; j < cnt; ++j) {
      float give = up ? acc[j] : acc[j + cnt];
      float keep = up ? acc[j + cnt] : acc[j];
      acc[j] = keep + __shfl_xor(give, mask);
    }
  }

  if (lane < 32) {
    const int r = lane >> 2, s_l = lane & 3;
    const int s_g = wave * 4 + s_l;
    const int bt = bt0 + r;
    if (s_g < 16) Bm[(size_t)bt * S_ + s_g] = acc[0];
    else          Cm[(size_t)bt * S_ + (s_g - 16)] = acc[0];
  }
}

// --------------------------------------------------------------------------
// Kernel 3: single-pass chained scan with decoupled lookback (hipCUB-style).
// Block = (c slowest, b, mt) so predecessors dispatch first. 128 thr =
// 64 m x 2 s-halves. dt/u held in REGISTERS across both passes; bm/cm in LDS.
// Pass A: local scan -> publish {AggA, AggH}, flag=1. Lookback (per-thread):
// walk predecessors; flag=2 slot is inclusive prefix -> stop. Publish own
// inclusive (IncH), flag=2. Pass B: replay with carry -> out.
// Flags zeroed by hipMemsetAsync each launch (graph-safe, deterministic).
// --------------------------------------------------------------------------
__global__ __launch_bounds__(128) void scan_single(
    const float* __restrict__ dt_ws,   // [B*T][M]
    const float* __restrict__ u,       // [B*T][M]
    const float* __restrict__ Bm,      // [B*T][S]
    const float* __restrict__ Cm,      // [B*T][S]
    const float* __restrict__ A_log,   // [S][M]
    const float* __restrict__ D,       // [M]
    float* __restrict__ AggA,          // [B][NC][S][M]
    float* __restrict__ AggH,          // [B][NC][S][M]
    float* __restrict__ IncH,          // [B][NC][S][M]
    int*   __restrict__ flags,         // [NC*B*NMT]
    float* __restrict__ out)           // [B*T][M]
{
  __shared__ float bm_lds[CL * S_];    // 1 KB
  __shared__ float cm_lds[CL * S_];    // 1 KB

  const int tid = threadIdx.x;
  const int bid = blockIdx.x;                  // c*(B*NMT) + b*NMT + mt
  const int mt  = bid % NMT;
  const int b   = (bid / NMT) % B_;
  const int c   = bid / (NMT * B_);
  const int m0  = mt * 64;
  const size_t row0 = (size_t)b * T_ + (size_t)c * CL;

  const int lane = tid & 63, wv = tid >> 6;
  const int m_l = wv * 32 + (lane & 31);       // 0..63
  const int sh  = lane >> 5, s0 = sh * 8;
  const int m   = m0 + m_l;

  // ---- stage bm/cm (coalesced) ----
  {
    const size_t bcb = row0 * S_;
    bm_lds[tid]       = Bm[bcb + tid];
    bm_lds[tid + 128] = Bm[bcb + tid + 128];
    cm_lds[tid]       = Cm[bcb + tid];
    cm_lds[tid + 128] = Cm[bcb + tid + 128];
  }

  // ---- dt/u into registers (coalesced across lanes per t) ----
  float dtv[CL], uv[CL];
  #pragma unroll
  for (int t = 0; t < CL; ++t) {
    const size_t gi = (row0 + t) * M_ + m;
    dtv[t] = dt_ws[gi];
    uv[t]  = u[gi];
  }

  float A2[8];
  #pragma unroll
  for (int s = 0; s < 8; ++s) {
    const float a = -__expf(A_log[(size_t)(s0 + s) * M_ + m]);
    A2[s] = fminf(fmaxf(a, -10.f), -1e-6f) * LOG2E;
  }
  const float Dm = D[m];
  __syncthreads();   // bm/cm ready

  // ---- pass A: local scan (h_in = 0) ----
  float h[8], Sla[8];
  #pragma unroll
  for (int s = 0; s < 8; ++s) { h[s] = 0.f; Sla[s] = 0.f; }
  #pragma unroll
  for (int t = 0; t < CL; ++t) {
    const float du = dtv[t] * uv[t];
    const float4 bv0 = *reinterpret_cast<const float4*>(&bm_lds[t * S_ + s0]);
    const float4 bv1 = *reinterpret_cast<const float4*>(&bm_lds[t * S_ + s0 + 4]);
    const float bmv[8] = {bv0.x, bv0.y, bv0.z, bv0.w, bv1.x, bv1.y, bv1.z, bv1.w};
    #pragma unroll
    for (int s = 0; s < 8; ++s) {
      const float la = fmaxf(dtv[t] * A2[s], LOG2_EPS);
      h[s] = fmaf(exp2f(la), h[s], du * bmv[s]);
      Sla[s] += la;
    }
  }

  // ---- publish aggregate ----
  const size_t smb = (((size_t)b * NC + c) * S_ + s0) * M_ + m;
  float Aloc[8];
  #pragma unroll
  for (int s = 0; s < 8; ++s) {
    Aloc[s] = exp2f(Sla[s]);
    AggA[smb + (size_t)s * M_] = Aloc[s];
    AggH[smb + (size_t)s * M_] = h[s];
  }
  __threadfence();
  __syncthreads();
  if (tid == 0) atomicExch(&flags[bid], 1);

  // ---- lookback (per-thread independent walk) ----
  float hin[8];
  #pragma unroll
  for (int s = 0; s < 8; ++s) hin[s] = 0.f;
  if (c > 0) {
    float P[8];
    #pragma unroll
    for (int s = 0; s < 8; ++s) P[s] = 1.f;
    int pc = c - 1;
    int pbid = bid - NMT * B_;
    while (true) {
      int f;
      while ((f = atomicAdd(&flags[pbid], 0)) == 0) {
        __builtin_amdgcn_s_sleep(2);
      }
      __threadfence();   // acquire predecessor's published data
      const size_t psmb = (((size_t)b * NC + pc) * S_ + s0) * M_ + m;
      if (f == 2) {
        #pragma unroll
        for (int s = 0; s < 8; ++s)
          hin[s] = fmaf(P[s], IncH[psmb + (size_t)s * M_], hin[s]);
        break;
      } else {
        #pragma unroll
        for (int s = 0; s < 8; ++s) {
          hin[s] = fmaf(P[s], AggH[psmb + (size_t)s * M_], hin[s]);
          P[s] *= AggA[psmb + (size_t)s * M_];
        }
        if (pc == 0) break;
        --pc; pbid -= NMT * B_;
      }
    }
  }

  // ---- publish inclusive prefix ----
  #pragma unroll
  for (int s = 0; s < 8; ++s)
    IncH[smb + (size_t)s * M_] = fmaf(Aloc[s], hin[s], h[s]);
  __threadfence();
  __syncthreads();
  if (tid == 0) atomicExch(&flags[bid], 2);

  // ---- pass B: replay with carry, write out ----
  #pragma unroll
  for (int s = 0; s < 8; ++s) h[s] = hin[s];
  #pragma unroll
  for (int t = 0; t < CL; ++t) {
    const float du = dtv[t] * uv[t];
    const float4 bv0 = *reinterpret_cast<const float4*>(&bm_lds[t * S_ + s0]);
    const float4 bv1 = *reinterpret_cast<const float4*>(&bm_lds[t * S_ + s0 + 4]);
    const float bmv[8] = {bv0.x, bv0.y, bv0.z, bv0.w, bv1.x, bv1.y, bv1.z, bv1.w};
    const float4 cv0 = *reinterpret_cast<const float4*>(&cm_lds[t * S_ + s0]);
    const float4 cv1 = *reinterpret_cast<const float4*>(&cm_lds[t * S_ + s0 + 4]);
    const float cmv[8] = {cv0.x, cv0.y, cv0.z, cv0.w, cv1.x, cv1.y, cv1.z, cv1.w};
    float y = 0.f;
    #pragma unroll
    for (int s = 0; s < 8; ++s) {
      const float la = fmaxf(dtv[t] * A2[s], LOG2_EPS);
      h[s] = fmaf(exp2f(la), h[s], du * bmv[s]);
      y = fmaf(h[s], cmv[s], y);
    }
    y += __shfl_xor(y, 32);
    if (sh == 0) {
      const float o = y + uv[t] * Dm;
      out[(row0 + t) * M_ + m] = fminf(fmaxf(o, -1e4f), 1e4f);
    }
  }
}

// --------------------------------------------------------------------------
extern "C" void kernel_launch(void* const* d_in, const int* in_sizes, int n_in,
                              void* d_out, int out_size, void* d_ws, size_t ws_size,
                              hipStream_t stream)
{
  const float* u     = (const float*)d_in[0];
  const float* delta = (const float*)d_in[1];
  const float* dt_w  = (const float*)d_in[2];
  const float* dt_b  = (const float*)d_in[3];
  const float* A_log = (const float*)d_in[4];
  const float* B_w   = (const float*)d_in[5];
  const float* C_w   = (const float*)d_in[6];
  const float* D     = (const float*)d_in[7];
  float* out = (float*)d_out;
  float* ws  = (float*)d_ws;

  const size_t fl_dt = (size_t)B_ * T_ * M_;   // 3,145,728
  const size_t fl_bc = (size_t)B_ * T_ * S_;   // 65,536
  const size_t fl_sm = (size_t)B_ * NC * MS_;  // 3,145,728

  float* dt_ws = ws;
  float* Bm    = dt_ws + fl_dt;
  float* Cm    = Bm + fl_bc;
  float* AggA  = Cm + fl_bc;
  float* AggH  = AggA + fl_sm;
  float* IncH  = AggH + fl_sm;
  int*   flags = (int*)(IncH + fl_sm);         // 3072 ints; ~51.6 MB total (ws = 256 MiB)

  hipMemsetAsync(flags, 0, sizeof(int) * NC * B_ * NMT, stream);
  dt_kernel<<<dim3(M_ / 64, (B_ * T_) / 64), 256, 0, stream>>>(delta, dt_w, dt_b, dt_ws);
  bc_kernel<<<dim3((B_ * T_) / 8), 512, 0, stream>>>(u, B_w, C_w, Bm, Cm);
  scan_single<<<dim3(NC * B_ * NMT), 128, 0, stream>>>(
      dt_ws, u, Bm, Cm, A_log, D, AggA, AggH, IncH, flags, out);
}

// Round 11
// 93.138 us; speedup vs baseline: 13.6292x; 13.6292x over previous
//
#include <hip/hip_runtime.h>
#include <math.h>

// Problem constants (match reference)
#define B_ 2
#define T_ 2048
#define M_ 768
#define R_ 64
#define S_ 16
#define MS_ (M_ * S_)
#define NC 128
#define CL 16              // T_ / NC
#define NCPB 4             // chunks per persistent scan block
#define NCG (NC / NCPB)    // 32 chunk-groups
#define LOG2E 1.4426950408889634f
#define LOG2_EPS (-33.219280948873623f)   // log2(1e-10)

// --------------------------------------------------------------------------
// Kernel 1 (round-5 proven): dt = clip(softplus(delta . dt_w^T + b)).
// Tiled 64x64, K=64, LDS transpose staging, coalesced everywhere.
// --------------------------------------------------------------------------
__global__ __launch_bounds__(256) void dt_kernel(
    const float* __restrict__ delta,   // [B*T][R]
    const float* __restrict__ dt_w,    // [M][R]
    const float* __restrict__ dt_b,    // [M]
    float* __restrict__ dt_out)        // [B*T][M]
{
  __shared__ float ds_d[R_][68];
  __shared__ float ds_w[R_][68];
  const int tid = threadIdx.x;
  const int m0  = blockIdx.x * 64;
  const int bt0 = blockIdx.y * 64;

  #pragma unroll
  for (int k = 0; k < 4; ++k) {
    int idx = tid + k * 256;
    int rq = idx & 15;
    int x  = idx >> 4;
    float4 dv = *reinterpret_cast<const float4*>(&delta[(size_t)(bt0 + x) * R_ + rq * 4]);
    ds_d[rq * 4 + 0][x] = dv.x; ds_d[rq * 4 + 1][x] = dv.y;
    ds_d[rq * 4 + 2][x] = dv.z; ds_d[rq * 4 + 3][x] = dv.w;
    float4 wv = *reinterpret_cast<const float4*>(&dt_w[(size_t)(m0 + x) * R_ + rq * 4]);
    ds_w[rq * 4 + 0][x] = wv.x; ds_w[rq * 4 + 1][x] = wv.y;
    ds_w[rq * 4 + 2][x] = wv.z; ds_w[rq * 4 + 3][x] = wv.w;
  }
  __syncthreads();

  const int mq = tid & 15, tq = tid >> 4;
  const int ml = mq * 4, tl = tq * 4;
  float acc[4][4] = {};
  #pragma unroll 4
  for (int r = 0; r < R_; ++r) {
    float4 dv = *reinterpret_cast<const float4*>(&ds_d[r][tl]);
    float4 wv = *reinterpret_cast<const float4*>(&ds_w[r][ml]);
    float d[4] = {dv.x, dv.y, dv.z, dv.w};
    float w[4] = {wv.x, wv.y, wv.z, wv.w};
    #pragma unroll
    for (int i = 0; i < 4; ++i)
      #pragma unroll
      for (int j = 0; j < 4; ++j)
        acc[i][j] = fmaf(d[i], w[j], acc[i][j]);
  }

  float4 bb = *reinterpret_cast<const float4*>(&dt_b[m0 + ml]);
  float bv[4] = {bb.x, bb.y, bb.z, bb.w};
  #pragma unroll
  for (int i = 0; i < 4; ++i) {
    float4 o;
    float* op = &o.x;
    #pragma unroll
    for (int j = 0; j < 4; ++j) {
      float x = acc[i][j] + bv[j];
      float sp = (x > 20.f) ? x : __logf(1.f + __expf(x));
      op[j] = fminf(fmaxf(sp, 1e-6f), 10.f);
    }
    *reinterpret_cast<float4*>(&dt_out[(size_t)(bt0 + tl + i) * M_ + m0 + ml]) = o;
  }
}

// --------------------------------------------------------------------------
// Kernel 2 (bc v6, proven): register-cached W slices, fold+pack butterfly.
// --------------------------------------------------------------------------
__global__ __launch_bounds__(512, 4) void bc_kernel(
    const float* __restrict__ u,     // [B*T][M]
    const float* __restrict__ B_w,   // [S][M]
    const float* __restrict__ C_w,   // [S][M]
    float* __restrict__ Bm,          // [B*T][S]
    float* __restrict__ Cm)          // [B*T][S]
{
  const int wave = threadIdx.x >> 6, lane = threadIdx.x & 63;
  const int bt0 = blockIdx.x * 8;

  float4 w[4][3];
  #pragma unroll
  for (int s = 0; s < 4; ++s) {
    const int s_g = wave * 4 + s;
    const float* wr = (s_g < 16) ? &B_w[(size_t)s_g * M_] : &C_w[(size_t)(s_g - 16) * M_];
    const float4* w4 = reinterpret_cast<const float4*>(wr);
    w[s][0] = w4[lane]; w[s][1] = w4[64 + lane]; w[s][2] = w4[128 + lane];
  }

  float acc[32];
  #pragma unroll
  for (int r = 0; r < 8; ++r) {
    const float4* ur = reinterpret_cast<const float4*>(&u[(size_t)(bt0 + r) * M_]);
    const float4 a0 = ur[lane], a1 = ur[64 + lane], a2 = ur[128 + lane];
    #pragma unroll
    for (int s = 0; s < 4; ++s) {
      float t = 0.f;
      t = fmaf(a0.x, w[s][0].x, t); t = fmaf(a0.y, w[s][0].y, t);
      t = fmaf(a0.z, w[s][0].z, t); t = fmaf(a0.w, w[s][0].w, t);
      t = fmaf(a1.x, w[s][1].x, t); t = fmaf(a1.y, w[s][1].y, t);
      t = fmaf(a1.z, w[s][1].z, t); t = fmaf(a1.w, w[s][1].w, t);
      t = fmaf(a2.x, w[s][2].x, t); t = fmaf(a2.y, w[s][2].y, t);
      t = fmaf(a2.z, w[s][2].z, t); t = fmaf(a2.w, w[s][2].w, t);
      acc[r * 4 + s] = t;
    }
  }

  #pragma unroll
  for (int j = 0; j < 32; ++j) acc[j] += __shfl_xor(acc[j], 32);
  int cnt = 32;
  #pragma unroll
  for (int mask = 16; mask >= 1; mask >>= 1) {
    cnt >>= 1;
    const bool up = (lane & mask) != 0;
    #pragma unroll
    for (int j = 0; j < cnt; ++j) {
      float give = up ? acc[j] : acc[j + cnt];
      float keep = up ? acc[j + cnt] : acc[j];
      acc[j] = keep + __shfl_xor(give, mask);
    }
  }

  if (lane < 32) {
    const int r = lane >> 2, s_l = lane & 3;
    const int s_g = wave * 4 + s_l;
    const int bt = bt0 + r;
    if (s_g < 16) Bm[(size_t)bt * S_ + s_g] = acc[0];
    else          Cm[(size_t)bt * S_ + (s_g - 16)] = acc[0];
  }
}

// --------------------------------------------------------------------------
// Kernels 3 & 5 (scan v7): persistent blocks, 4 chunks each, double-buffered
// prefetch. Block = (mt, cgroup, b), 128 thr = 64 m x 2 s-halves. While chunk
// c is scanned (dt/u in registers set A/B, bm/cm in LDS buf 0/1), chunk c+1's
// global loads are in flight into the other set. One barrier per buffer swap.
// No inter-block dependencies. exp2-domain decay. Summaries [B][NC][S][M];
// Aprod doubles as the carry buffer after kernel 4.
// --------------------------------------------------------------------------
#define PREFETCH_CHUNK(cc, DT, U, HP, NB0, NB1, NCV0, NCV1)                    \
  {                                                                            \
    const size_t prow = (size_t)b * T_ + (size_t)(cc) * CL;                    \
    _Pragma("unroll")                                                          \
    for (int k = 0; k < CL; ++k) {                                             \
      DT[k] = dt_ws[(prow + k) * M_ + m];                                      \
      U[k]  = u[(prow + k) * M_ + m];                                          \
    }                                                                          \
    NB0 = Bm[prow * S_ + tid];                                                 \
    NB1 = Bm[prow * S_ + tid + 128];                                           \
    if constexpr (PHASE == 3) {                                                \
      NCV0 = Cm[prow * S_ + tid];                                              \
      NCV1 = Cm[prow * S_ + tid + 128];                                        \
      const size_t psmb = (((size_t)b * NC + (cc)) * S_ + s0) * M_ + m;        \
      _Pragma("unroll")                                                        \
      for (int s = 0; s < 8; ++s) HP[s] = Aprod[psmb + (size_t)s * M_];        \
    }                                                                          \
  }

#define SCAN_CHUNK(cc, DT, U, BUF, HP)                                         \
  {                                                                            \
    const size_t srow = (size_t)b * T_ + (size_t)(cc) * CL;                    \
    float h[8], Sl[8];                                                         \
    if constexpr (PHASE == 1) {                                                \
      _Pragma("unroll")                                                        \
      for (int s = 0; s < 8; ++s) { h[s] = 0.f; Sl[s] = 0.f; }                 \
    } else {                                                                   \
      _Pragma("unroll")                                                        \
      for (int s = 0; s < 8; ++s) h[s] = HP[s];                                \
    }                                                                          \
    _Pragma("unroll")                                                          \
    for (int t = 0; t < CL; ++t) {                                             \
      const float du = DT[t] * U[t];                                           \
      const float4 bv0 = *reinterpret_cast<const float4*>(&bm_lds[BUF][t * S_ + s0]);      \
      const float4 bv1 = *reinterpret_cast<const float4*>(&bm_lds[BUF][t * S_ + s0 + 4]);  \
      const float bmv[8] = {bv0.x, bv0.y, bv0.z, bv0.w, bv1.x, bv1.y, bv1.z, bv1.w};       \
      float cmv[8];                                                            \
      if constexpr (PHASE == 3) {                                              \
        const float4 cv0 = *reinterpret_cast<const float4*>(&cm_lds[BUF][t * S_ + s0]);     \
        const float4 cv1 = *reinterpret_cast<const float4*>(&cm_lds[BUF][t * S_ + s0 + 4]); \
        cmv[0] = cv0.x; cmv[1] = cv0.y; cmv[2] = cv0.z; cmv[3] = cv0.w;        \
        cmv[4] = cv1.x; cmv[5] = cv1.y; cmv[6] = cv1.z; cmv[7] = cv1.w;        \
      }                                                                        \
      float y = 0.f;                                                           \
      _Pragma("unroll")                                                        \
      for (int s = 0; s < 8; ++s) {                                            \
        const float la = fmaxf(DT[t] * A2[s], LOG2_EPS);                       \
        const float e = exp2f(la);                                             \
        h[s] = fmaf(e, h[s], du * bmv[s]);                                     \
        if constexpr (PHASE == 1) Sl[s] += la;                                 \
        else y = fmaf(h[s], cmv[s], y);                                        \
      }                                                                        \
      if constexpr (PHASE == 3) {                                              \
        y += __shfl_xor(y, 32);                                                \
        if (sh == 0) {                                                         \
          const float o = y + U[t] * Dm;                                       \
          out[(srow + t) * M_ + m] = fminf(fmaxf(o, -1e4f), 1e4f);             \
        }                                                                      \
      }                                                                        \
    }                                                                          \
    if constexpr (PHASE == 1) {                                                \
      const size_t wsmb = (((size_t)b * NC + (cc)) * S_ + s0) * M_ + m;        \
      _Pragma("unroll")                                                        \
      for (int s = 0; s < 8; ++s) {                                            \
        Aprod[wsmb + (size_t)s * M_] = exp2f(Sl[s]);                           \
        Hend[wsmb + (size_t)s * M_]  = h[s];                                   \
      }                                                                        \
    }                                                                          \
  }

template <int PHASE>
__global__ __launch_bounds__(128) void scan_v7(
    const float* __restrict__ dt_ws,   // [B*T][M]
    const float* __restrict__ u,       // [B*T][M]
    const float* __restrict__ Bm,      // [B*T][S]
    const float* __restrict__ Cm,      // [B*T][S]
    const float* __restrict__ A_log,   // [S][M]
    const float* __restrict__ D,       // [M]
    float* __restrict__ Aprod,         // [B][NC][S][M]; carry after kernel 4
    float* __restrict__ Hend,          // [B][NC][S][M]
    float* __restrict__ out)           // [B*T][M]
{
  __shared__ float bm_lds[2][CL * S_];   // 2 KB
  __shared__ float cm_lds[2][CL * S_];   // 2 KB

  const int tid = threadIdx.x;
  const int mt = blockIdx.x;               // 0..11
  const int cg = blockIdx.y;               // 0..31
  const int b  = blockIdx.z;
  const int m0 = mt * 64;
  const int c0 = cg * NCPB;

  const int lane = tid & 63, wv = tid >> 6;
  const int m_l = wv * 32 + (lane & 31);   // 0..63
  const int sh = lane >> 5, s0 = sh * 8;
  const int m = m0 + m_l;

  float A2[8];
  #pragma unroll
  for (int s = 0; s < 8; ++s) {
    const float a = -__expf(A_log[(size_t)(s0 + s) * M_ + m]);
    A2[s] = fminf(fmaxf(a, -10.f), -1e-6f) * LOG2E;
  }
  float Dm = 0.f;
  if constexpr (PHASE == 3) Dm = D[m];

  float dtA[CL], uA[CL], dtB[CL], uB[CL];
  float hpA[8], hpB[8];
  float nb0, nb1, ncv0, ncv1;
  (void)hpA; (void)hpB; (void)ncv0; (void)ncv1;

  // ---- prologue: chunk c0 -> set A + LDS buf0 (direct) ----
  {
    const size_t prow = (size_t)b * T_ + (size_t)c0 * CL;
    #pragma unroll
    for (int k = 0; k < CL; ++k) {
      dtA[k] = dt_ws[(prow + k) * M_ + m];
      uA[k]  = u[(prow + k) * M_ + m];
    }
    bm_lds[0][tid]       = Bm[prow * S_ + tid];
    bm_lds[0][tid + 128] = Bm[prow * S_ + tid + 128];
    if constexpr (PHASE == 3) {
      cm_lds[0][tid]       = Cm[prow * S_ + tid];
      cm_lds[0][tid + 128] = Cm[prow * S_ + tid + 128];
      const size_t psmb = (((size_t)b * NC + c0) * S_ + s0) * M_ + m;
      #pragma unroll
      for (int s = 0; s < 8; ++s) hpA[s] = Aprod[psmb + (size_t)s * M_];
    }
  }
  __syncthreads();

  // ---- main loop: pairs of chunks, A/B register sets, buf 0/1 ----
  #pragma unroll
  for (int cp = 0; cp < NCPB / 2; ++cp) {
    const int cA = c0 + cp * 2;

    // prefetch odd chunk into set B (loads in flight during SCAN of cA)
    PREFETCH_CHUNK(cA + 1, dtB, uB, hpB, nb0, nb1, ncv0, ncv1);
    SCAN_CHUNK(cA, dtA, uA, 0, hpA);
    bm_lds[1][tid] = nb0; bm_lds[1][tid + 128] = nb1;
    if constexpr (PHASE == 3) { cm_lds[1][tid] = ncv0; cm_lds[1][tid + 128] = ncv1; }
    __syncthreads();

    // prefetch next pair's even chunk into set A
    if (cp < NCPB / 2 - 1) {
      PREFETCH_CHUNK(cA + 2, dtA, uA, hpA, nb0, nb1, ncv0, ncv1);
    }
    SCAN_CHUNK(cA + 1, dtB, uB, 1, hpB);
    if (cp < NCPB / 2 - 1) {
      bm_lds[0][tid] = nb0; bm_lds[0][tid + 128] = nb1;
      if constexpr (PHASE == 3) { cm_lds[0][tid] = ncv0; cm_lds[0][tid + 128] = ncv1; }
      __syncthreads();
    }
  }
}

// --------------------------------------------------------------------------
// Kernel 4: chunk-carry combine, in place (NC=128): Aprod[c] read (decay
// product) then overwritten with the carry entering chunk c.
// --------------------------------------------------------------------------
__global__ __launch_bounds__(256) void carry_kernel(
    float* __restrict__ Aprod, const float* __restrict__ Hend)
{
  const int idx = blockIdx.x * 256 + threadIdx.x;  // over B*S*M
  const int b = idx / MS_;
  const int sm = idx - b * MS_;
  float h = 0.f;
  #pragma unroll 16
  for (int c = 0; c < NC; ++c) {
    const size_t o = ((size_t)b * NC + c) * MS_ + sm;
    const float a  = Aprod[o];
    const float he = Hend[o];
    Aprod[o] = h;                 // carry into chunk c
    h = fmaf(a, h, he);
  }
}

// --------------------------------------------------------------------------
extern "C" void kernel_launch(void* const* d_in, const int* in_sizes, int n_in,
                              void* d_out, int out_size, void* d_ws, size_t ws_size,
                              hipStream_t stream)
{
  const float* u     = (const float*)d_in[0];
  const float* delta = (const float*)d_in[1];
  const float* dt_w  = (const float*)d_in[2];
  const float* dt_b  = (const float*)d_in[3];
  const float* A_log = (const float*)d_in[4];
  const float* B_w   = (const float*)d_in[5];
  const float* C_w   = (const float*)d_in[6];
  const float* D     = (const float*)d_in[7];
  float* out = (float*)d_out;
  float* ws  = (float*)d_ws;

  const size_t fl_dt = (size_t)B_ * T_ * M_;   // 3,145,728
  const size_t fl_bc = (size_t)B_ * T_ * S_;   // 65,536
  const size_t fl_sm = (size_t)B_ * NC * MS_;  // 3,145,728

  float* dt_ws = ws;
  float* Bm    = dt_ws + fl_dt;
  float* Cm    = Bm + fl_bc;
  float* Aprod = Cm + fl_bc;         // later holds carries
  float* Hend  = Aprod + fl_sm;      // total ~38 MB

  dt_kernel<<<dim3(M_ / 64, (B_ * T_) / 64), 256, 0, stream>>>(delta, dt_w, dt_b, dt_ws);
  bc_kernel<<<dim3((B_ * T_) / 8), 512, 0, stream>>>(u, B_w, C_w, Bm, Cm);
  scan_v7<1><<<dim3(M_ / 64, NCG, B_), 128, 0, stream>>>(
      dt_ws, u, Bm, Cm, A_log, D, Aprod, Hend, nullptr);
  carry_kernel<<<dim3((B_ * MS_) / 256), 256, 0, stream>>>(Aprod, Hend);
  scan_v7<3><<<dim3(M_ / 64, NCG, B_), 128, 0, stream>>>(
      dt_ws, u, Bm, Cm, A_log, D, Aprod, Hend, out);
}

// Round 12
// 80.480 us; speedup vs baseline: 15.7730x; 1.1573x over previous
//
#include <hip/hip_runtime.h>
#include <math.h>

// Problem constants (match reference)
#define B_ 2
#define T_ 2048
#define M_ 768
#define R_ 64
#define S_ 16
#define MS_ (M_ * S_)
#define NC 128
#define CL 16              // T_ / NC
#define LOG2E 1.4426950408889634f
#define LOG2_EPS (-33.219280948873623f)   // log2(1e-10)

// --------------------------------------------------------------------------
// Kernel 1 (merged projections): blocks 0..511 do Bm/Cm (bc v6, proven);
// blocks 512..895 do dt = clip(softplus(delta . dt_w^T + b)) on 128bt x 64m
// tiles (R5 dt kernel scaled to 512 threads). Uniform block-level branch.
// --------------------------------------------------------------------------
__global__ __launch_bounds__(512, 4) void proj_kernel(
    const float* __restrict__ u,       // [B*T][M]
    const float* __restrict__ delta,   // [B*T][R]
    const float* __restrict__ dt_w,    // [M][R]
    const float* __restrict__ dt_b,    // [M]
    const float* __restrict__ B_w,     // [S][M]
    const float* __restrict__ C_w,     // [S][M]
    float* __restrict__ dt_out,        // [B*T][M]
    float* __restrict__ Bm,            // [B*T][S]
    float* __restrict__ Cm)            // [B*T][S]
{
  __shared__ float ds_d[R_][132];   // [r][bt 0..127], padded
  __shared__ float ds_w[R_][68];    // [r][m 0..63], padded

  const int tid = threadIdx.x;

  if (blockIdx.x < 512) {
    // ---------------- bc path (proven v6) ----------------
    const int wave = tid >> 6, lane = tid & 63;
    const int bt0 = blockIdx.x * 8;

    float4 w[4][3];
    #pragma unroll
    for (int s = 0; s < 4; ++s) {
      const int s_g = wave * 4 + s;
      const float* wr = (s_g < 16) ? &B_w[(size_t)s_g * M_] : &C_w[(size_t)(s_g - 16) * M_];
      const float4* w4 = reinterpret_cast<const float4*>(wr);
      w[s][0] = w4[lane]; w[s][1] = w4[64 + lane]; w[s][2] = w4[128 + lane];
    }

    float acc[32];
    #pragma unroll
    for (int r = 0; r < 8; ++r) {
      const float4* ur = reinterpret_cast<const float4*>(&u[(size_t)(bt0 + r) * M_]);
      const float4 a0 = ur[lane], a1 = ur[64 + lane], a2 = ur[128 + lane];
      #pragma unroll
      for (int s = 0; s < 4; ++s) {
        float t = 0.f;
        t = fmaf(a0.x, w[s][0].x, t); t = fmaf(a0.y, w[s][0].y, t);
        t = fmaf(a0.z, w[s][0].z, t); t = fmaf(a0.w, w[s][0].w, t);
        t = fmaf(a1.x, w[s][1].x, t); t = fmaf(a1.y, w[s][1].y, t);
        t = fmaf(a1.z, w[s][1].z, t); t = fmaf(a1.w, w[s][1].w, t);
        t = fmaf(a2.x, w[s][2].x, t); t = fmaf(a2.y, w[s][2].y, t);
        t = fmaf(a2.z, w[s][2].z, t); t = fmaf(a2.w, w[s][2].w, t);
        acc[r * 4 + s] = t;
      }
    }

    #pragma unroll
    for (int j = 0; j < 32; ++j) acc[j] += __shfl_xor(acc[j], 32);
    int cnt = 32;
    #pragma unroll
    for (int mask = 16; mask >= 1; mask >>= 1) {
      cnt >>= 1;
      const bool up = (lane & mask) != 0;
      #pragma unroll
      for (int j = 0; j < cnt; ++j) {
        float give = up ? acc[j] : acc[j + cnt];
        float keep = up ? acc[j + cnt] : acc[j];
        acc[j] = keep + __shfl_xor(give, mask);
      }
    }

    if (lane < 32) {
      const int r = lane >> 2, s_l = lane & 3;
      const int s_g = wave * 4 + s_l;
      const int bt = bt0 + r;
      if (s_g < 16) Bm[(size_t)bt * S_ + s_g] = acc[0];
      else          Cm[(size_t)bt * S_ + (s_g - 16)] = acc[0];
    }
  } else {
    // ---------------- dt path (R5 kernel, 128bt x 64m tile) ----------------
    const int bid2 = blockIdx.x - 512;       // 0..383
    const int mt = bid2 % (M_ / 64);         // 0..11
    const int bt0 = (bid2 / (M_ / 64)) * 128;
    const int m0 = mt * 64;

    // stage delta^T: 2048 float4
    #pragma unroll
    for (int k = 0; k < 4; ++k) {
      int idx = tid + k * 512;
      int rq = idx & 15;
      int x  = idx >> 4;                      // 0..127
      float4 dv = *reinterpret_cast<const float4*>(&delta[(size_t)(bt0 + x) * R_ + rq * 4]);
      ds_d[rq * 4 + 0][x] = dv.x; ds_d[rq * 4 + 1][x] = dv.y;
      ds_d[rq * 4 + 2][x] = dv.z; ds_d[rq * 4 + 3][x] = dv.w;
    }
    // stage dt_w^T: 1024 float4
    #pragma unroll
    for (int k = 0; k < 2; ++k) {
      int idx = tid + k * 512;
      int rq = idx & 15;
      int x  = idx >> 4;                      // 0..63
      float4 wv = *reinterpret_cast<const float4*>(&dt_w[(size_t)(m0 + x) * R_ + rq * 4]);
      ds_w[rq * 4 + 0][x] = wv.x; ds_w[rq * 4 + 1][x] = wv.y;
      ds_w[rq * 4 + 2][x] = wv.z; ds_w[rq * 4 + 3][x] = wv.w;
    }
    __syncthreads();

    const int mq = tid & 15, tq = tid >> 4;   // tq 0..31
    const int ml = mq * 4, tl = tq * 4;
    float acc[4][4] = {};
    #pragma unroll 4
    for (int r = 0; r < R_; ++r) {
      float4 dv = *reinterpret_cast<const float4*>(&ds_d[r][tl]);
      float4 wv = *reinterpret_cast<const float4*>(&ds_w[r][ml]);
      float d[4] = {dv.x, dv.y, dv.z, dv.w};
      float w[4] = {wv.x, wv.y, wv.z, wv.w};
      #pragma unroll
      for (int i = 0; i < 4; ++i)
        #pragma unroll
        for (int j = 0; j < 4; ++j)
          acc[i][j] = fmaf(d[i], w[j], acc[i][j]);
    }

    float4 bb = *reinterpret_cast<const float4*>(&dt_b[m0 + ml]);
    float bv[4] = {bb.x, bb.y, bb.z, bb.w};
    #pragma unroll
    for (int i = 0; i < 4; ++i) {
      float4 o;
      float* op = &o.x;
      #pragma unroll
      for (int j = 0; j < 4; ++j) {
        float x = acc[i][j] + bv[j];
        float sp = (x > 20.f) ? x : __logf(1.f + __expf(x));
        op[j] = fminf(fmaxf(sp, 1e-6f), 10.f);
      }
      *reinterpret_cast<float4*>(&dt_out[(size_t)(bt0 + tl + i) * M_ + m0 + ml]) = o;
    }
  }
}

// --------------------------------------------------------------------------
// Kernels 2 & 4 (scan v8): R5 geometry (NC=128, CL=16, 3072 single-shot
// blocks of 128 thr = 64 m x 2 s-halves, LDS-staged dt/u/bm/cm) with a
// batched-exp inner loop: per 4-step group, all 32 independent exp2 values
// are computed first (saturates trans pipe), then the pure-FMA h-updates.
// exp2-domain decay (verified numerics). Summaries [B][NC][S][M];
// Aprod doubles as the carry buffer after kernel 3.
// --------------------------------------------------------------------------
template <int PHASE>
__global__ __launch_bounds__(128) void scan_v8(
    const float* __restrict__ dt_ws,   // [B*T][M]
    const float* __restrict__ u,       // [B*T][M]
    const float* __restrict__ Bm,      // [B*T][S]
    const float* __restrict__ Cm,      // [B*T][S]
    const float* __restrict__ A_log,   // [S][M]
    const float* __restrict__ D,       // [M]
    float* __restrict__ Aprod,         // [B][NC][S][M]; carry after kernel 3
    float* __restrict__ Hend,          // [B][NC][S][M]
    float* __restrict__ out)           // [B*T][M]
{
  __shared__ float dt_lds[CL][64];     // 4 KB
  __shared__ float u_lds[CL][64];      // 4 KB
  __shared__ float bm_lds[CL * S_];    // 1 KB
  __shared__ float cm_lds[CL * S_];    // 1 KB

  const int tid = threadIdx.x;
  const int mt = blockIdx.x;               // 0..11
  const int c  = blockIdx.y;               // 0..127
  const int b  = blockIdx.z;
  const int m0 = mt * 64;
  const size_t row0 = (size_t)b * T_ + (size_t)c * CL;

  // ---- stage dt/u ([16][64], coalesced float4) + bm/cm ----
  #pragma unroll
  for (int p = 0; p < 2; ++p) {
    const int i4 = tid + p * 128;
    const int t = i4 >> 4, m4 = (i4 & 15) * 4;
    *reinterpret_cast<float4*>(&dt_lds[t][m4]) =
        *reinterpret_cast<const float4*>(&dt_ws[(row0 + t) * M_ + m0 + m4]);
    *reinterpret_cast<float4*>(&u_lds[t][m4]) =
        *reinterpret_cast<const float4*>(&u[(row0 + t) * M_ + m0 + m4]);
  }
  {
    const size_t bcb = row0 * S_;
    bm_lds[tid]       = Bm[bcb + tid];
    bm_lds[tid + 128] = Bm[bcb + tid + 128];
    if constexpr (PHASE == 3) {
      cm_lds[tid]       = Cm[bcb + tid];
      cm_lds[tid + 128] = Cm[bcb + tid + 128];
    }
  }

  const int lane = tid & 63, wv = tid >> 6;
  const int m_l = wv * 32 + (lane & 31);   // 0..63
  const int sh = lane >> 5, s0 = sh * 8;
  const int m = m0 + m_l;

  float A2[8];
  #pragma unroll
  for (int s = 0; s < 8; ++s) {
    const float a = -__expf(A_log[(size_t)(s0 + s) * M_ + m]);
    A2[s] = fminf(fmaxf(a, -10.f), -1e-6f) * LOG2E;
  }

  float h[8], Sla[8], Dm = 0.f;
  const size_t smb = (((size_t)b * NC + c) * S_ + s0) * M_ + m;
  if constexpr (PHASE == 1) {
    #pragma unroll
    for (int s = 0; s < 8; ++s) { h[s] = 0.f; Sla[s] = 0.f; }
  } else {
    #pragma unroll
    for (int s = 0; s < 8; ++s) h[s] = Aprod[smb + (size_t)s * M_];  // carry
    Dm = D[m];
  }
  __syncthreads();

  // ---- scan: groups of 4 t-steps; batch the 32 exps, then FMA block ----
  #pragma unroll
  for (int tg = 0; tg < CL; tg += 4) {
    float e[4][8], dus[4];
    #pragma unroll
    for (int k = 0; k < 4; ++k) {
      const float dtv = dt_lds[tg + k][m_l];
      dus[k] = dtv * u_lds[tg + k][m_l];
      #pragma unroll
      for (int s = 0; s < 8; ++s) {
        const float la = fmaxf(dtv * A2[s], LOG2_EPS);
        e[k][s] = exp2f(la);
        if constexpr (PHASE == 1) Sla[s] += la;
      }
    }
    #pragma unroll
    for (int k = 0; k < 4; ++k) {
      const int t = tg + k;
      const float4 bv0 = *reinterpret_cast<const float4*>(&bm_lds[t * S_ + s0]);
      const float4 bv1 = *reinterpret_cast<const float4*>(&bm_lds[t * S_ + s0 + 4]);
      const float bmv[8] = {bv0.x, bv0.y, bv0.z, bv0.w, bv1.x, bv1.y, bv1.z, bv1.w};
      float cmv[8];
      if constexpr (PHASE == 3) {
        const float4 cv0 = *reinterpret_cast<const float4*>(&cm_lds[t * S_ + s0]);
        const float4 cv1 = *reinterpret_cast<const float4*>(&cm_lds[t * S_ + s0 + 4]);
        cmv[0] = cv0.x; cmv[1] = cv0.y; cmv[2] = cv0.z; cmv[3] = cv0.w;
        cmv[4] = cv1.x; cmv[5] = cv1.y; cmv[6] = cv1.z; cmv[7] = cv1.w;
      }
      float y = 0.f;
      #pragma unroll
      for (int s = 0; s < 8; ++s) {
        h[s] = fmaf(e[k][s], h[s], dus[k] * bmv[s]);
        if constexpr (PHASE == 3) y = fmaf(h[s], cmv[s], y);
      }
      if constexpr (PHASE == 3) {
        y += __shfl_xor(y, 32);
        if (sh == 0) {
          const float o = y + u_lds[t][m_l] * Dm;
          out[(row0 + t) * M_ + m] = fminf(fmaxf(o, -1e4f), 1e4f);
        }
      }
    }
  }

  if constexpr (PHASE == 1) {
    #pragma unroll
    for (int s = 0; s < 8; ++s) {
      Aprod[smb + (size_t)s * M_] = exp2f(Sla[s]);   // chunk decay product
      Hend[smb + (size_t)s * M_]  = h[s];
    }
  }
}

// --------------------------------------------------------------------------
// Kernel 3: chunk-carry combine, in place (NC=128): Aprod[c] read (decay
// product) then overwritten with the carry entering chunk c.
// --------------------------------------------------------------------------
__global__ __launch_bounds__(256) void carry_kernel(
    float* __restrict__ Aprod, const float* __restrict__ Hend)
{
  const int idx = blockIdx.x * 256 + threadIdx.x;  // over B*S*M
  const int b = idx / MS_;
  const int sm = idx - b * MS_;
  float h = 0.f;
  #pragma unroll 16
  for (int c = 0; c < NC; ++c) {
    const size_t o = ((size_t)b * NC + c) * MS_ + sm;
    const float a  = Aprod[o];
    const float he = Hend[o];
    Aprod[o] = h;                 // carry into chunk c
    h = fmaf(a, h, he);
  }
}

// --------------------------------------------------------------------------
extern "C" void kernel_launch(void* const* d_in, const int* in_sizes, int n_in,
                              void* d_out, int out_size, void* d_ws, size_t ws_size,
                              hipStream_t stream)
{
  const float* u     = (const float*)d_in[0];
  const float* delta = (const float*)d_in[1];
  const float* dt_w  = (const float*)d_in[2];
  const float* dt_b  = (const float*)d_in[3];
  const float* A_log = (const float*)d_in[4];
  const float* B_w   = (const float*)d_in[5];
  const float* C_w   = (const float*)d_in[6];
  const float* D     = (const float*)d_in[7];
  float* out = (float*)d_out;
  float* ws  = (float*)d_ws;

  const size_t fl_dt = (size_t)B_ * T_ * M_;   // 3,145,728
  const size_t fl_bc = (size_t)B_ * T_ * S_;   // 65,536
  const size_t fl_sm = (size_t)B_ * NC * MS_;  // 3,145,728

  float* dt_ws = ws;
  float* Bm    = dt_ws + fl_dt;
  float* Cm    = Bm + fl_bc;
  float* Aprod = Cm + fl_bc;         // later holds carries
  float* Hend  = Aprod + fl_sm;      // total ~38 MB (ws = 256 MiB)

  // merged projections: 512 bc blocks + 384 dt blocks
  proj_kernel<<<dim3(512 + (M_ / 64) * ((B_ * T_) / 128)), 512, 0, stream>>>(
      u, delta, dt_w, dt_b, B_w, C_w, dt_ws, Bm, Cm);
  scan_v8<1><<<dim3(M_ / 64, NC, B_), 128, 0, stream>>>(
      dt_ws, u, Bm, Cm, A_log, D, Aprod, Hend, nullptr);
  carry_kernel<<<dim3((B_ * MS_) / 256), 256, 0, stream>>>(Aprod, Hend);
  scan_v8<3><<<dim3(M_ / 64, NC, B_), 128, 0, stream>>>(
      dt_ws, u, Bm, Cm, A_log, D, Aprod, Hend, out);
}